// Round 2
// baseline (266.682 us; speedup 1.0000x reference)
//
#include <hip/hip_runtime.h>
#include <hip/hip_bf16.h>
#include <math.h>

// LoRA attention, MI355X bf16-MFMA pipeline, round 2.
// cast x->bf16 | fold Weff=W+B@A (one kernel) | ONE merged proj GEMM (QK row-major, V transposed)
// | scores GEMM (bf16 P) | row softmax | PV GEMM with in-block split-K (8 waves).

typedef __attribute__((ext_vector_type(4))) float f32x4;
typedef __attribute__((ext_vector_type(8))) short bf8;   // 8 x bf16
typedef __attribute__((ext_vector_type(4))) short bf4;   // 4 x bf16

__device__ __forceinline__ float bf2f(unsigned short b) {
  union { unsigned u; float f; } c; c.u = ((unsigned)b) << 16; return c.f;
}
__device__ __forceinline__ unsigned short f2bf(float f) {
  union { float f; unsigned u; } c; c.f = f;
  return (unsigned short)((c.u + 0x7fffu + ((c.u >> 16) & 1u)) >> 16);
}
__device__ __forceinline__ void gload16(const void* g, void* l) {
  __builtin_amdgcn_global_load_lds((const __attribute__((address_space(1))) void*)g,
                                   (__attribute__((address_space(3))) void*)l, 16, 0, 0);
}

// ---------------- cast fp32 -> bf16, 8 elems/thread ----------------
__global__ __launch_bounds__(256)
void k_cast(const float* __restrict__ x, __hip_bfloat16* __restrict__ o) {
  long i = ((long)blockIdx.x * 256 + threadIdx.x) * 8;
  float4 a = *(const float4*)&x[i];
  float4 b = *(const float4*)&x[i + 4];
  union { bf8 v; unsigned short h[8]; } u;
  u.h[0] = f2bf(a.x); u.h[1] = f2bf(a.y); u.h[2] = f2bf(a.z); u.h[3] = f2bf(a.w);
  u.h[4] = f2bf(b.x); u.h[5] = f2bf(b.y); u.h[6] = f2bf(b.z); u.h[7] = f2bf(b.w);
  *(bf8*)&o[i] = u.v;
}

// ---------------- Weff = W + B@A for all three, concat [2304][768] bf16 ----------------
__global__ __launch_bounds__(256)
void k_fold3(const float* __restrict__ W0, const float* __restrict__ A0, const float* __restrict__ B0,
             const float* __restrict__ W1, const float* __restrict__ A1, const float* __restrict__ B1,
             const float* __restrict__ W2, const float* __restrict__ A2, const float* __restrict__ B2,
             __hip_bfloat16* __restrict__ out) {
  int idx = blockIdx.x * 256 + threadIdx.x;        // 0..1769471
  int t = idx / 589824, j = idx - t * 589824;
  const float* W = (t == 0) ? W0 : (t == 1) ? W1 : W2;
  const float* A = (t == 0) ? A0 : (t == 1) ? A1 : A2;
  const float* Bl = (t == 0) ? B0 : (t == 1) ? B1 : B2;
  int d = j % 768, o = j / 768;
  float acc = W[j];
  #pragma unroll
  for (int r = 0; r < 32; ++r) acc += Bl[o * 32 + r] * A[r * 768 + d];
  out[idx] = __float2bfloat16(acc);
}

// ---------------- GEMM: Out[m][n] = scale * sum_k A[m][k]*B[n][k] (+bias[n]) ----------
// 128x128 tile, BK=32, 4 waves (2x2), 4x4 16x16x32 frags/wave, XCD-swizzled blocks.
// OUT_MODE: 1 = bf16 row-major (ldo)
//           3 = merged proj: col<1536 -> bf16 row-major ld 1536 into Og;
//                            col>=1536 -> bf16 transposed [768][8192] into Og2
template<int OUT_MODE>
__global__ __launch_bounds__(256, 2)
void k_gemm(const __hip_bfloat16* __restrict__ Ag, const __hip_bfloat16* __restrict__ Bg,
            const float* __restrict__ bias, void* __restrict__ Og, void* __restrict__ Og2,
            int K, int lda, int ldb, int ldo,
            long sA, long sB, long sO, float scale)
{
  __shared__ __hip_bfloat16 As[128 * 32];
  __shared__ __hip_bfloat16 Bs[128 * 32];
  const int tid = threadIdx.x;
  const int wave = tid >> 6, lane = tid & 63;
  const long z = blockIdx.z;
  const __hip_bfloat16* A = Ag + z * sA;
  const __hip_bfloat16* B = Bg + z * sB;

  // XCD-aware swizzle (requires gridDim.x*gridDim.y % 8 == 0; all launches satisfy)
  const int nwg = gridDim.x * gridDim.y;
  const int wid0 = blockIdx.y * gridDim.x + blockIdx.x;
  const int wid = (wid0 & 7) * (nwg >> 3) + (wid0 >> 3);
  const long arow0 = (long)(wid % gridDim.x) * 128;
  const long brow0 = (long)(wid / gridDim.x) * 128;

  f32x4 acc[4][4] = {};

  const int e0 = wave * 1024 + lane * 8;
  const int r0 = e0 >> 5, c0 = e0 & 31;
  const int e1 = e0 + 512;
  const int r1 = e1 >> 5, c1 = e1 & 31;

  const int wm = wave >> 1, wn = wave & 1;
  const int arow_f = wm * 64 + (lane & 15);
  const int brow_f = wn * 64 + (lane & 15);
  const int kf = (lane >> 4) * 8;

  for (int k0 = 0; k0 < K; k0 += 32) {
    __syncthreads();
    gload16(A + (arow0 + r0) * (long)lda + k0 + c0, As + wave * 1024);
    gload16(A + (arow0 + r1) * (long)lda + k0 + c1, As + wave * 1024 + 512);
    gload16(B + (brow0 + r0) * (long)ldb + k0 + c0, Bs + wave * 1024);
    gload16(B + (brow0 + r1) * (long)ldb + k0 + c1, Bs + wave * 1024 + 512);
    __syncthreads();

    bf8 af[4], bfv[4];
    #pragma unroll
    for (int m = 0; m < 4; ++m) af[m]  = *(const bf8*)&As[(arow_f + m * 16) * 32 + kf];
    #pragma unroll
    for (int n = 0; n < 4; ++n) bfv[n] = *(const bf8*)&Bs[(brow_f + n * 16) * 32 + kf];
    #pragma unroll
    for (int m = 0; m < 4; ++m)
      #pragma unroll
      for (int n = 0; n < 4; ++n)
        acc[m][n] = __builtin_amdgcn_mfma_f32_16x16x32_bf16(af[m], bfv[n], acc[m][n], 0, 0, 0);
  }

  // epilogue: C/D map col=lane&15, row=(lane>>4)*4+r
  #pragma unroll
  for (int m = 0; m < 4; ++m) {
    const long rb = arow0 + wm * 64 + m * 16 + ((lane >> 4) << 2);
    #pragma unroll
    for (int n = 0; n < 4; ++n) {
      const long cb = brow0 + wn * 64 + n * 16 + (lane & 15);
      const float bv = bias ? bias[cb] : 0.0f;
      if constexpr (OUT_MODE == 1) {
        __hip_bfloat16* O = (__hip_bfloat16*)Og + z * sO;
        #pragma unroll
        for (int r = 0; r < 4; ++r)
          *(unsigned short*)&O[(rb + r) * (long)ldo + cb] = f2bf(acc[m][n][r] * scale + bv);
      } else {  // mode 3
        if (cb < 1536) {
          __hip_bfloat16* O = (__hip_bfloat16*)Og;
          #pragma unroll
          for (int r = 0; r < 4; ++r)
            *(unsigned short*)&O[(rb + r) * 1536 + cb] = f2bf(acc[m][n][r] + bv);
        } else {
          __hip_bfloat16* O2 = (__hip_bfloat16*)Og2;
          bf4 v;
          #pragma unroll
          for (int r = 0; r < 4; ++r) v[r] = (short)f2bf(acc[m][n][r] + bv);
          *(bf4*)&O2[(cb - 1536) * 8192 + rb] = v;
        }
      }
    }
  }
}

// ---------------- PV GEMM with in-block split-K ----------------
// out[m][n] = sum_k P[m][k] * Vt[n][k], M=4096 N=768 K=4096 per batch.
// 512 threads = 8 waves: (kh = wave>>2) K-half, (wm,wn) 2x2 over 128x128 tile.
// Each wave: 4x4 16x16 frags over its 2048-long K half; LDS reduce at end.
__global__ __launch_bounds__(512, 2)
void k_gemm_sk(const __hip_bfloat16* __restrict__ Pg, const __hip_bfloat16* __restrict__ Vtg,
               float* __restrict__ Og)
{
  __shared__ __hip_bfloat16 smem[2][2][4096];   // [half][A=0/B=1][128*32] = 32 KiB
  const int tid = threadIdx.x;
  const int wave = tid >> 6, lane = tid & 63;
  const int kh = wave >> 2, s = wave & 3;
  const int wm = (wave >> 1) & 1, wn = wave & 1;
  const long z = blockIdx.z;
  const __hip_bfloat16* A = Pg + z * (4096L * 4096);
  const __hip_bfloat16* B = Vtg + z * 4096;

  const int nwg = gridDim.x * gridDim.y;           // 192, %8==0
  const int wid0 = blockIdx.y * gridDim.x + blockIdx.x;
  const int wid = (wid0 & 7) * (nwg >> 3) + (wid0 >> 3);
  const long arow0 = (long)(wid % gridDim.x) * 128;
  const long brow0 = (long)(wid / gridDim.x) * 128;

  f32x4 acc[4][4] = {};

  // staging: wave (kh,s) stages its own K-half; rows s*16..s*16+15 and +64
  const __hip_bfloat16* Asrc = A + (arow0 + s * 16 + (lane >> 2)) * 4096L + kh * 2048 + (lane & 3) * 8;
  const __hip_bfloat16* Bsrc = B + (brow0 + s * 16 + (lane >> 2)) * 8192L + kh * 2048 + (lane & 3) * 8;
  __hip_bfloat16* dA = &smem[kh][0][s * 512];
  __hip_bfloat16* dB = &smem[kh][1][s * 512];

  const __hip_bfloat16* Ah = &smem[kh][0][0];
  const __hip_bfloat16* Bh = &smem[kh][1][0];
  const int arow_f = wm * 64 + (lane & 15);
  const int brow_f = wn * 64 + (lane & 15);
  const int kf = (lane >> 4) * 8;

  for (int it = 0; it < 64; ++it) {
    const int ko = it * 32;
    __syncthreads();
    gload16(Asrc + ko, dA);
    gload16(Asrc + 64 * 4096L + ko, dA + 2048);
    gload16(Bsrc + ko, dB);
    gload16(Bsrc + 64 * 8192L + ko, dB + 2048);
    __syncthreads();

    bf8 af[4], bfv[4];
    #pragma unroll
    for (int m = 0; m < 4; ++m) af[m]  = *(const bf8*)&Ah[(arow_f + m * 16) * 32 + kf];
    #pragma unroll
    for (int n = 0; n < 4; ++n) bfv[n] = *(const bf8*)&Bh[(brow_f + n * 16) * 32 + kf];
    #pragma unroll
    for (int m = 0; m < 4; ++m)
      #pragma unroll
      for (int n = 0; n < 4; ++n)
        acc[m][n] = __builtin_amdgcn_mfma_f32_16x16x32_bf16(af[m], bfv[n], acc[m][n], 0, 0, 0);
  }

  // cross-half reduction through LDS (two 32 KiB rounds: m-pairs)
  float* red = (float*)&smem[0][0][0];
  #pragma unroll
  for (int half = 0; half < 2; ++half) {
    __syncthreads();
    if (kh == 1) {
      #pragma unroll
      for (int mm = 0; mm < 2; ++mm)
        #pragma unroll
        for (int n = 0; n < 4; ++n)
          *(f32x4*)&red[(((s * 8) + mm * 4 + n) * 64 + lane) * 4] = acc[half * 2 + mm][n];
    }
    __syncthreads();
    if (kh == 0) {
      #pragma unroll
      for (int mm = 0; mm < 2; ++mm)
        #pragma unroll
        for (int n = 0; n < 4; ++n) {
          f32x4 o = *(const f32x4*)&red[(((s * 8) + mm * 4 + n) * 64 + lane) * 4];
          acc[half * 2 + mm][n] += o;
        }
    }
  }

  if (kh == 0) {
    float* O = Og + z * (4096L * 768);
    #pragma unroll
    for (int m = 0; m < 4; ++m) {
      const long rb = arow0 + wm * 64 + m * 16 + ((lane >> 4) << 2);
      #pragma unroll
      for (int n = 0; n < 4; ++n) {
        const long cb = brow0 + wn * 64 + n * 16 + (lane & 15);
        #pragma unroll
        for (int r = 0; r < 4; ++r) O[(rb + r) * 768 + cb] = acc[m][n][r];
      }
    }
  }
}

// ---------------- row softmax in place, row = 4096 bf16 ----------------
__global__ __launch_bounds__(256)
void k_softmax(__hip_bfloat16* __restrict__ P) {
  const int S = 4096;
  __hip_bfloat16* p = P + (long)blockIdx.x * S;
  const int tid = threadIdx.x, lane = tid & 63, wave = tid >> 6;
  __shared__ float red[8];
  float x[16];
  bf8 a = *(const bf8*)&p[tid * 16];
  bf8 b = *(const bf8*)&p[tid * 16 + 8];
  #pragma unroll
  for (int j = 0; j < 8; ++j) { x[j] = bf2f((unsigned short)a[j]); x[8 + j] = bf2f((unsigned short)b[j]); }
  float mx = x[0];
  #pragma unroll
  for (int j = 1; j < 16; ++j) mx = fmaxf(mx, x[j]);
  #pragma unroll
  for (int o = 32; o; o >>= 1) mx = fmaxf(mx, __shfl_xor(mx, o));
  if (lane == 0) red[wave] = mx;
  __syncthreads();
  mx = fmaxf(fmaxf(red[0], red[1]), fmaxf(red[2], red[3]));
  float s = 0.0f;
  #pragma unroll
  for (int j = 0; j < 16; ++j) { x[j] = __expf(x[j] - mx); s += x[j]; }
  #pragma unroll
  for (int o = 32; o; o >>= 1) s += __shfl_xor(s, o);
  if (lane == 0) red[4 + wave] = s;
  __syncthreads();
  const float inv = 1.0f / (red[4] + red[5] + red[6] + red[7]);
  union { bf8 v; unsigned short h[8]; } u0, u1;
  #pragma unroll
  for (int j = 0; j < 8; ++j) { u0.h[j] = f2bf(x[j] * inv); u1.h[j] = f2bf(x[8 + j] * inv); }
  *(bf8*)&p[tid * 16] = u0.v;
  *(bf8*)&p[tid * 16 + 8] = u1.v;
}

extern "C" void kernel_launch(void* const* d_in, const int* in_sizes, int n_in,
                              void* d_out, int out_size, void* d_ws, size_t ws_size,
                              hipStream_t stream) {
  const float* x  = (const float*)d_in[0];
  const float* Wq = (const float*)d_in[1]; const float* bq = (const float*)d_in[2];
  const float* Wk = (const float*)d_in[3]; const float* bk = (const float*)d_in[4];
  const float* Wv = (const float*)d_in[5]; const float* bv = (const float*)d_in[6];
  const float* Aq = (const float*)d_in[7]; const float* Bq = (const float*)d_in[8];
  const float* Ak = (const float*)d_in[9]; const float* Bk = (const float*)d_in[10];
  const float* Av = (const float*)d_in[11]; const float* Bv = (const float*)d_in[12];

  // ws layout (bf16 elems), ~121 MB total
  __hip_bfloat16* Xb   = (__hip_bfloat16*)d_ws;        // [8192][768]
  __hip_bfloat16* WeA  = Xb  + 6291456;                // [2304][768]
  __hip_bfloat16* Vt   = WeA + 1769472;                // [768][8192]
  __hip_bfloat16* QKb  = Vt  + 6291456;                // [8192][1536] (Q cols 0-767, K 768-1535)
  __hip_bfloat16* Pb   = QKb + 12582912;               // [2][4096][4096]
  float*          bcat = (float*)(Pb + 33554432);      // [2304]
  float* out = (float*)d_out;

  k_cast<<<3072, 256, 0, stream>>>(x, Xb);
  k_fold3<<<6912, 256, 0, stream>>>(Wq, Aq, Bq, Wk, Ak, Bk, Wv, Av, Bv, WeA);
  hipMemcpyAsync(bcat,        bq, 768 * sizeof(float), hipMemcpyDeviceToDevice, stream);
  hipMemcpyAsync(bcat +  768, bk, 768 * sizeof(float), hipMemcpyDeviceToDevice, stream);
  hipMemcpyAsync(bcat + 1536, bv, 768 * sizeof(float), hipMemcpyDeviceToDevice, stream);

  // merged projections: M=8192, N=2304, K=768
  k_gemm<3><<<dim3(64, 18, 1), 256, 0, stream>>>(Xb, WeA, bcat, QKb, Vt,
                                                 768, 768, 768, 1536, 0, 0, 0, 1.0f);
  // scores: per batch M=N=4096, K=768; A=Q (ld 1536), B=K (ld 1536)
  const float sc = 0.036084391824351615f;
  k_gemm<1><<<dim3(32, 32, 2), 256, 0, stream>>>(QKb, QKb + 768, nullptr, Pb, nullptr,
                                                 768, 1536, 1536, 4096,
                                                 4096L * 1536, 4096L * 1536, 4096L * 4096, sc);
  k_softmax<<<8192, 256, 0, stream>>>(Pb);
  // PV with in-block split-K
  k_gemm_sk<<<dim3(32, 6, 2), 512, 0, stream>>>(Pb, Vt, out);
}

// Round 3
// 254.595 us; speedup vs baseline: 1.0475x; 1.0475x over previous
//
#include <hip/hip_runtime.h>
#include <hip/hip_bf16.h>
#include <math.h>

// LoRA attention, MI355X bf16-MFMA pipeline, round 3.
// 8-phase 256x256x64 GEMM template (T1 XCD swizzle + T2 LDS XOR swizzle +
// T3/T4 counted-vmcnt phase pipeline + T5 setprio) for proj / scores / PV.

typedef __attribute__((ext_vector_type(4))) float f32x4;
typedef __attribute__((ext_vector_type(8))) short bf8;   // 8 x bf16
typedef __attribute__((ext_vector_type(4))) short bf4;   // 4 x bf16

__device__ __forceinline__ float bf2f(unsigned short b) {
  union { unsigned u; float f; } c; c.u = ((unsigned)b) << 16; return c.f;
}
__device__ __forceinline__ unsigned short f2bf(float f) {
  union { float f; unsigned u; } c; c.f = f;
  return (unsigned short)((c.u + 0x7fffu + ((c.u >> 16) & 1u)) >> 16);
}
__device__ __forceinline__ void gload16(const void* g, void* l) {
  __builtin_amdgcn_global_load_lds((const __attribute__((address_space(1))) void*)g,
                                   (__attribute__((address_space(3))) void*)l, 16, 0, 0);
}

// ---------------- cast fp32 -> bf16 ----------------
__global__ __launch_bounds__(256)
void k_cast(const float* __restrict__ x, __hip_bfloat16* __restrict__ o) {
  long i = ((long)blockIdx.x * 256 + threadIdx.x) * 8;
  float4 a = *(const float4*)&x[i];
  float4 b = *(const float4*)&x[i + 4];
  union { bf8 v; unsigned short h[8]; } u;
  u.h[0] = f2bf(a.x); u.h[1] = f2bf(a.y); u.h[2] = f2bf(a.z); u.h[3] = f2bf(a.w);
  u.h[4] = f2bf(b.x); u.h[5] = f2bf(b.y); u.h[6] = f2bf(b.z); u.h[7] = f2bf(b.w);
  *(bf8*)&o[i] = u.v;
}

// ---------------- Weff = W + B@A, concat [2304][768] bf16 ----------------
__global__ __launch_bounds__(256)
void k_fold3(const float* __restrict__ W0, const float* __restrict__ A0, const float* __restrict__ B0,
             const float* __restrict__ W1, const float* __restrict__ A1, const float* __restrict__ B1,
             const float* __restrict__ W2, const float* __restrict__ A2, const float* __restrict__ B2,
             __hip_bfloat16* __restrict__ out) {
  int idx = blockIdx.x * 256 + threadIdx.x;
  int t = idx / 589824, j = idx - t * 589824;
  const float* W = (t == 0) ? W0 : (t == 1) ? W1 : W2;
  const float* A = (t == 0) ? A0 : (t == 1) ? A1 : A2;
  const float* Bl = (t == 0) ? B0 : (t == 1) ? B1 : B2;
  int d = j % 768, o = j / 768;
  float acc = W[j];
  #pragma unroll
  for (int r = 0; r < 32; ++r) acc += Bl[o * 32 + r] * A[r * 768 + d];
  out[idx] = __float2bfloat16(acc);
}

// ---------------- 8-phase GEMM phase body ----------------
// Reads one quadrant (A-half MH x B-half NH) of the current K-tile buffer,
// issues one half-tile prefetch stage (2 x global_load_lds / wave),
// barrier, 16 MFMA, [vmcnt(4) if group end], barrier.
template<int MH, int NH, bool GEND>
__device__ __forceinline__ void phase_full(const char* __restrict__ Ab, const char* __restrict__ Bb,
                                           int wm, int wn, int lane, f32x4 (&acc)[8][4],
                                           const __hip_bfloat16* gsrc, long gld, char* ldst)
{
  const int lnlo = lane & 15, lnhi = lane >> 4;
  bf8 af[4][2], bv[2][2];
  #pragma unroll
  for (int m = 0; m < 4; ++m) {
    const int row = wm * 64 + m * 16 + lnlo;
    #pragma unroll
    for (int k = 0; k < 2; ++k) {
      const int sb = (k * 64 + lnhi * 16) ^ ((row & 7) << 4);   // T2 XOR swizzle
      af[m][k] = *(const bf8*)(Ab + row * 128 + sb);
    }
  }
  #pragma unroll
  for (int n = 0; n < 2; ++n) {
    const int row = wn * 32 + n * 16 + lnlo;
    #pragma unroll
    for (int k = 0; k < 2; ++k) {
      const int sb = (k * 64 + lnhi * 16) ^ ((row & 7) << 4);
      bv[n][k] = *(const bf8*)(Bb + row * 128 + sb);
    }
  }
  // stage one half-tile (targets a slot retired in the previous phase)
  gload16(gsrc, ldst);
  gload16(gsrc + 8 * gld, ldst + 1024);
  asm volatile("" ::: "memory");
  __builtin_amdgcn_s_barrier();
  __builtin_amdgcn_s_setprio(1);
  #pragma unroll
  for (int m = 0; m < 4; ++m)
    #pragma unroll
    for (int n = 0; n < 2; ++n) {
      acc[MH*4+m][NH*2+n] = __builtin_amdgcn_mfma_f32_16x16x32_bf16(af[m][0], bv[n][0], acc[MH*4+m][NH*2+n], 0, 0, 0);
      acc[MH*4+m][NH*2+n] = __builtin_amdgcn_mfma_f32_16x16x32_bf16(af[m][1], bv[n][1], acc[MH*4+m][NH*2+n], 0, 0, 0);
    }
  __builtin_amdgcn_s_setprio(0);
  if (GEND) asm volatile("s_waitcnt vmcnt(4)" ::: "memory");
  __builtin_amdgcn_s_barrier();
  asm volatile("" ::: "memory");
}

// ---------------- 8-phase 256x256x64 GEMM ----------------
// Out[m][n] = scale * sum_k A[m][k] * B[n][k]  (row-major A, "B rows = out cols")
// MODE 0: PV, fp32 out, split-K2 (z = batch*2+split; split0 -> Og, split1 -> Og2)
// MODE 1: scores, bf16 out ld 4096, per-batch z, scale
// MODE 3: proj, col<1536 -> bf16 [8192][1536] Og (+bias); col>=1536 -> Vt [768][8192] Og2 (+bias)
template<int MODE>
__global__ __launch_bounds__(512, 2)
void k_gemm8(const __hip_bfloat16* __restrict__ Ag, const __hip_bfloat16* __restrict__ Bg,
             const float* __restrict__ bias, void* __restrict__ Og, void* __restrict__ Og2,
             float scale)
{
  __shared__ short lds[2][2][2][8192];   // [buf][opA/B][half][128*64] = 128 KiB
  constexpr int NT = (MODE == 0) ? 32 : 12;
  const int tid = threadIdx.x, w = tid >> 6, lane = tid & 63;
  const int wm = w >> 2, wn = w & 3;

  // T1: XCD-aware swizzle (nwg % 8 == 0 for all launches)
  const int nx = gridDim.x;
  const int nwg = nx * gridDim.y;
  const int w0 = blockIdx.y * nx + blockIdx.x;
  const int cpx = nwg >> 3;
  const int wid = (w0 & 7) * cpx + (w0 >> 3);
  const long M0 = (long)(wid % nx) * 256;
  const long N0 = (long)(wid / nx) * 256;

  const __hip_bfloat16 *A, *B; long lda, ldb;
  float* Of = nullptr; __hip_bfloat16* Ob = nullptr;
  if constexpr (MODE == 0) {
    const int batch = blockIdx.z >> 1, split = blockIdx.z & 1;
    A = Ag + (long)batch * 4096 * 4096 + (long)split * 2048; lda = 4096;
    B = Bg + (long)batch * 4096 + (long)split * 2048;        ldb = 8192;
    Of = (float*)(split ? Og2 : Og) + (long)batch * 4096 * 768;
  } else if constexpr (MODE == 1) {
    A = Ag + (long)blockIdx.z * 4096 * 1536; B = A + 768; lda = 1536; ldb = 1536;
    Ob = (__hip_bfloat16*)Og + (long)blockIdx.z * 4096 * 4096;
  } else {
    A = Ag; B = Bg; lda = 768; ldb = 768;
  }

  // per-lane staging source bases (global col pre-swizzled = T2 inverse on source)
  const int rr = w * 16 + (lane >> 3);
  const int sl8 = ((lane & 7) ^ (rr & 7)) * 8;
  const __hip_bfloat16* pA[2]; const __hip_bfloat16* pB[2];
  #pragma unroll
  for (int h = 0; h < 2; ++h) {
    pA[h] = A + (M0 + (long)((rr >> 6) * 128 + h * 64 + (rr & 63))) * lda + sl8;
    pB[h] = B + (N0 + (long)((rr >> 5) * 64 + h * 32 + (rr & 31))) * ldb + sl8;
  }
  char* Lc = (char*)lds;
  const int woff = w * 2048;                        // wave-uniform LDS dest
  auto dstp = [&](int op, int h, int d) { return Lc + d * 65536 + op * 32768 + h * 16384 + woff; };

  f32x4 acc[8][4] = {};

  // prologue: tile0 {Ah0,Ah1,Bh0,Bh1}->buf0, then tile1 {Bh0,Ah0}->buf1
  gload16(pA[0],            dstp(0,0,0)); gload16(pA[0] + 8*lda,      dstp(0,0,0) + 1024);
  gload16(pA[1],            dstp(0,1,0)); gload16(pA[1] + 8*lda,      dstp(0,1,0) + 1024);
  gload16(pB[0],            dstp(1,0,0)); gload16(pB[0] + 8*ldb,      dstp(1,0,0) + 1024);
  gload16(pB[1],            dstp(1,1,0)); gload16(pB[1] + 8*ldb,      dstp(1,1,0) + 1024);
  gload16(pB[0] + 64,       dstp(1,0,1)); gload16(pB[0] + 64 + 8*ldb, dstp(1,0,1) + 1024);
  gload16(pA[0] + 64,       dstp(0,0,1)); gload16(pA[0] + 64 + 8*lda, dstp(0,0,1) + 1024);
  asm volatile("s_waitcnt vmcnt(4)" ::: "memory");   // tile0's 4 halves landed
  __builtin_amdgcn_s_barrier();
  asm volatile("" ::: "memory");

  for (int t = 0; t < NT; ++t) {
    const int d = t & 1;
    const int t1 = (t + 1 < NT) ? t + 1 : t - 1;   // clamp: benign identical re-stage
    const int t2 = (t + 2 < NT) ? t + 2 : t;
    const char* A0 = Lc + d * 65536;
    const char* A1 = A0 + 16384;
    const char* B0 = A0 + 32768;
    const char* B1 = B0 + 16384;
    phase_full<0,0,false>(A0, B0, wm, wn, lane, acc, pA[1] + t1*64, lda, dstp(0,1,d^1));
    phase_full<1,0,false>(A1, B0, wm, wn, lane, acc, pB[1] + t1*64, ldb, dstp(1,1,d^1));
    phase_full<0,1,false>(A0, B1, wm, wn, lane, acc, pB[0] + t2*64, ldb, dstp(1,0,d));
    phase_full<1,1,true >(A1, B1, wm, wn, lane, acc, pA[0] + t2*64, lda, dstp(0,0,d));
  }

  // epilogue: C/D map col=lane&15, row=(lane>>4)*4+r
  const int lnlo = lane & 15, lnhi = lane >> 4;
  #pragma unroll
  for (int mf = 0; mf < 8; ++mf) {
    const long row = M0 + wm * 128 + mf * 16 + lnhi * 4;
    #pragma unroll
    for (int nf = 0; nf < 4; ++nf) {
      const long col = N0 + wn * 64 + nf * 16 + lnlo;
      if constexpr (MODE == 0) {
        #pragma unroll
        for (int r = 0; r < 4; ++r) Of[(row + r) * 768 + col] = acc[mf][nf][r];
      } else if constexpr (MODE == 1) {
        #pragma unroll
        for (int r = 0; r < 4; ++r)
          *(unsigned short*)&Ob[(row + r) * 4096 + col] = f2bf(acc[mf][nf][r] * scale);
      } else {
        const float bvl = bias[col];
        if (col < 1536) {
          __hip_bfloat16* O = (__hip_bfloat16*)Og;
          #pragma unroll
          for (int r = 0; r < 4; ++r)
            *(unsigned short*)&O[(row + r) * 1536 + col] = f2bf(acc[mf][nf][r] + bvl);
        } else {
          __hip_bfloat16* O2 = (__hip_bfloat16*)Og2;
          bf4 v;
          #pragma unroll
          for (int r = 0; r < 4; ++r) v[r] = (short)f2bf(acc[mf][nf][r] + bvl);
          *(bf4*)&O2[(col - 1536) * 8192 + row] = v;
        }
      }
    }
  }
}

// ---------------- row softmax in place, row = 4096 bf16 ----------------
__global__ __launch_bounds__(256)
void k_softmax(__hip_bfloat16* __restrict__ P) {
  const int S = 4096;
  __hip_bfloat16* p = P + (long)blockIdx.x * S;
  const int tid = threadIdx.x, lane = tid & 63, wave = tid >> 6;
  __shared__ float red[8];
  float x[16];
  bf8 a = *(const bf8*)&p[tid * 16];
  bf8 b = *(const bf8*)&p[tid * 16 + 8];
  #pragma unroll
  for (int j = 0; j < 8; ++j) { x[j] = bf2f((unsigned short)a[j]); x[8 + j] = bf2f((unsigned short)b[j]); }
  float mx = x[0];
  #pragma unroll
  for (int j = 1; j < 16; ++j) mx = fmaxf(mx, x[j]);
  #pragma unroll
  for (int o = 32; o; o >>= 1) mx = fmaxf(mx, __shfl_xor(mx, o));
  if (lane == 0) red[wave] = mx;
  __syncthreads();
  mx = fmaxf(fmaxf(red[0], red[1]), fmaxf(red[2], red[3]));
  float s = 0.0f;
  #pragma unroll
  for (int j = 0; j < 16; ++j) { x[j] = __expf(x[j] - mx); s += x[j]; }
  #pragma unroll
  for (int o = 32; o; o >>= 1) s += __shfl_xor(s, o);
  if (lane == 0) red[4 + wave] = s;
  __syncthreads();
  const float inv = 1.0f / (red[4] + red[5] + red[6] + red[7]);
  union { bf8 v; unsigned short h[8]; } u0, u1;
  #pragma unroll
  for (int j = 0; j < 8; ++j) { u0.h[j] = f2bf(x[j] * inv); u1.h[j] = f2bf(x[8 + j] * inv); }
  *(bf8*)&p[tid * 16] = u0.v;
  *(bf8*)&p[tid * 16 + 8] = u1.v;
}

// ---------------- out += part (split-K reduce) ----------------
__global__ __launch_bounds__(256)
void k_add(float* __restrict__ out, const float* __restrict__ part) {
  long i = ((long)blockIdx.x * 256 + threadIdx.x) * 4;
  f32x4 a = *(const f32x4*)&out[i];
  f32x4 b = *(const f32x4*)&part[i];
  a += b;
  *(f32x4*)&out[i] = a;
}

extern "C" void kernel_launch(void* const* d_in, const int* in_sizes, int n_in,
                              void* d_out, int out_size, void* d_ws, size_t ws_size,
                              hipStream_t stream) {
  const float* x  = (const float*)d_in[0];
  const float* Wq = (const float*)d_in[1]; const float* bq = (const float*)d_in[2];
  const float* Wk = (const float*)d_in[3]; const float* bk = (const float*)d_in[4];
  const float* Wv = (const float*)d_in[5]; const float* bv = (const float*)d_in[6];
  const float* Aq = (const float*)d_in[7]; const float* Bq = (const float*)d_in[8];
  const float* Ak = (const float*)d_in[9]; const float* Bk = (const float*)d_in[10];
  const float* Av = (const float*)d_in[11]; const float* Bv = (const float*)d_in[12];

  // ws layout (bf16 elems), ~121 MB total; PV fp32 partial (25.2 MB) overlays
  // Xb+WeA+QKb (dead by PV time).
  __hip_bfloat16* Xb   = (__hip_bfloat16*)d_ws;        // [8192][768]
  __hip_bfloat16* WeA  = Xb  + 6291456;                // [2304][768]
  __hip_bfloat16* QKb  = WeA + 1769472;                // [8192][1536]
  __hip_bfloat16* Vt   = QKb + 12582912;               // [768][8192]
  __hip_bfloat16* Pb   = Vt  + 6291456;                // [2][4096][4096]
  float*          bcat = (float*)(Pb + 33554432);      // [2304]
  float*          part = (float*)d_ws;                 // [2][4096][768] fp32 overlay
  float* out = (float*)d_out;

  k_cast<<<3072, 256, 0, stream>>>(x, Xb);
  k_fold3<<<6912, 256, 0, stream>>>(Wq, Aq, Bq, Wk, Ak, Bk, Wv, Av, Bv, WeA);
  hipMemcpyAsync(bcat,        bq, 768 * sizeof(float), hipMemcpyDeviceToDevice, stream);
  hipMemcpyAsync(bcat +  768, bk, 768 * sizeof(float), hipMemcpyDeviceToDevice, stream);
  hipMemcpyAsync(bcat + 1536, bv, 768 * sizeof(float), hipMemcpyDeviceToDevice, stream);

  // merged projections: M=8192, N=2304, K=768
  k_gemm8<3><<<dim3(32, 9, 1), 512, 0, stream>>>(Xb, WeA, bcat, QKb, Vt, 1.0f);
  // scores: per batch M=N=4096, K=768, bf16 out with 1/sqrt(768)
  const float sc = 0.036084391824351615f;
  k_gemm8<1><<<dim3(16, 16, 2), 512, 0, stream>>>(QKb, nullptr, nullptr, Pb, nullptr, sc);
  k_softmax<<<8192, 256, 0, stream>>>(Pb);
  // PV: per batch M=4096, N=768, K=4096, split-K=2 (z = batch*2+split)
  k_gemm8<0><<<dim3(16, 3, 4), 512, 0, stream>>>(Pb, Vt, nullptr, out, part, 1.0f);
  k_add<<<6144, 256, 0, stream>>>(out, part);
}

// Round 4
// 221.491 us; speedup vs baseline: 1.2040x; 1.1495x over previous
//
#include <hip/hip_runtime.h>
#include <hip/hip_bf16.h>
#include <math.h>

// LoRA attention, MI355X bf16-MFMA pipeline, round 4.
// One 128x128x64 8-phase GEMM template (2 blocks/CU, reg-cached fragments,
// T1/T2/T4/T5) for proj / scores / PV. No split-K.

typedef __attribute__((ext_vector_type(4))) float f32x4;
typedef __attribute__((ext_vector_type(8))) short bf8;   // 8 x bf16
typedef __attribute__((ext_vector_type(4))) short bf4;   // 4 x bf16

__device__ __forceinline__ float bf2f(unsigned short b) {
  union { unsigned u; float f; } c; c.u = ((unsigned)b) << 16; return c.f;
}
__device__ __forceinline__ unsigned short f2bf(float f) {
  union { float f; unsigned u; } c; c.f = f;
  return (unsigned short)((c.u + 0x7fffu + ((c.u >> 16) & 1u)) >> 16);
}
__device__ __forceinline__ void gload16(const void* g, void* l) {
  __builtin_amdgcn_global_load_lds((const __attribute__((address_space(1))) void*)g,
                                   (__attribute__((address_space(3))) void*)l, 16, 0, 0);
}

// ---------------- cast fp32 -> bf16 ----------------
__global__ __launch_bounds__(256)
void k_cast(const float* __restrict__ x, __hip_bfloat16* __restrict__ o) {
  long i = ((long)blockIdx.x * 256 + threadIdx.x) * 8;
  float4 a = *(const float4*)&x[i];
  float4 b = *(const float4*)&x[i + 4];
  union { bf8 v; unsigned short h[8]; } u;
  u.h[0] = f2bf(a.x); u.h[1] = f2bf(a.y); u.h[2] = f2bf(a.z); u.h[3] = f2bf(a.w);
  u.h[4] = f2bf(b.x); u.h[5] = f2bf(b.y); u.h[6] = f2bf(b.z); u.h[7] = f2bf(b.w);
  *(bf8*)&o[i] = u.v;
}

// ---------------- Weff = W + B@A, concat [2304][768] bf16, + bias concat ----------------
__global__ __launch_bounds__(256)
void k_fold3(const float* __restrict__ W0, const float* __restrict__ A0, const float* __restrict__ B0,
             const float* __restrict__ W1, const float* __restrict__ A1, const float* __restrict__ B1,
             const float* __restrict__ W2, const float* __restrict__ A2, const float* __restrict__ B2,
             const float* __restrict__ bq, const float* __restrict__ bk, const float* __restrict__ bv,
             __hip_bfloat16* __restrict__ out, float* __restrict__ bcat) {
  int idx = blockIdx.x * 256 + threadIdx.x;
  if (idx < 2304)
    bcat[idx] = (idx < 768) ? bq[idx] : (idx < 1536) ? bk[idx - 768] : bv[idx - 1536];
  int t = idx / 589824, j = idx - t * 589824;
  const float* W = (t == 0) ? W0 : (t == 1) ? W1 : W2;
  const float* A = (t == 0) ? A0 : (t == 1) ? A1 : A2;
  const float* Bl = (t == 0) ? B0 : (t == 1) ? B1 : B2;
  int d = j % 768, o = j / 768;
  float acc = W[j];
  #pragma unroll
  for (int r = 0; r < 32; ++r) acc += Bl[o * 32 + r] * A[r * 768 + d];
  out[idx] = __float2bfloat16(acc);
}

// ---------------- 128x128x64 8-wave 8-phase GEMM ----------------
// Out[m][n] = scale * sum_k A[m][k] * B[n][k]
// MODE 0: PV   (A=P ld4096, B=Vt ld8192 +z*4096, fp32 out [4096][768])
// MODE 1: scores (A=Q ld1536, B=A+768, bf16 out ld4096, *scale)
// MODE 3: proj (col<1536 -> bf16 [8192][1536] +bias; else Vt [768][8192] +bias)
// Waves: wm=w>>2 (M 32-row slice), wn=w&3 (N 16-col slice); MH/NH phase halves.
template<int MODE>
__global__ __launch_bounds__(512, 4)
void k_g128(const __hip_bfloat16* __restrict__ Ag, const __hip_bfloat16* __restrict__ Bg,
            const float* __restrict__ bias, void* __restrict__ Og, void* __restrict__ Og2,
            float scale)
{
  __shared__ short lds[32768];   // 64 KiB: [buf2][opA/B][half2][64x64 bf16]
  constexpr int NT = (MODE == 0) ? 64 : 12;
  const int tid = threadIdx.x, w = tid >> 6, lane = tid & 63;
  const int wm = w >> 2, wn = w & 3;
  const int lnlo = lane & 15, lnhi = lane >> 4;

  // T1 XCD swizzle; N-fast tile mapping (n-blocks of one M-stripe share an XCD)
  const int gy = gridDim.y;
  const int nwg = gridDim.x * gy;
  const int w0 = blockIdx.y * gridDim.x + blockIdx.x;
  const int wid = (w0 & 7) * (nwg >> 3) + (w0 >> 3);
  const long M0 = (long)(wid / gy) * 128;
  const long N0 = (long)(wid % gy) * 128;

  const __hip_bfloat16 *A, *B; long lda, ldb;
  if constexpr (MODE == 0) {
    A = Ag + (long)blockIdx.z * 4096 * 4096; lda = 4096;
    B = Bg + (long)blockIdx.z * 4096;        ldb = 8192;
  } else if constexpr (MODE == 1) {
    A = Ag + (long)blockIdx.z * 4096 * 1536; B = A + 768; lda = 1536; ldb = 1536;
  } else {
    A = Ag; B = Bg; lda = 768; ldb = 768;
  }

  // staging: half-tile 64 rows x 64 cols = 1 gload16/wave; source col pre-swizzled (T2)
  const int srow = w * 8 + (lane >> 3);
  const int scol = (((lane & 7) ^ (lane >> 3)) << 3);
  const __hip_bfloat16* pA[2] = { A + (M0 + srow) * lda + scol, A + (M0 + 64 + srow) * lda + scol };
  const __hip_bfloat16* pB[2] = { B + (N0 + srow) * ldb + scol, B + (N0 + 64 + srow) * ldb + scol };
  char* Lc = (char*)lds;
  auto dstp = [&](int op, int h, int d) { return Lc + d * 32768 + op * 16384 + h * 8192 + w * 1024; };
  auto rd = [&](const char* base, int row, int k) -> bf8 {   // swizzled LDS read
    const int sb = ((k << 6) + (lnhi << 4)) ^ ((row & 7) << 4);
    return *(const bf8*)(base + row * 128 + sb);
  };

  f32x4 acc[4][2] = {};   // acc[MH*2+m][NH]

  // prologue: tile0 {A-h0,A-h1,B-h0,B-h1}, tile1 {A-h0,B-h0}
  gload16(pA[0], dstp(0,0,0)); gload16(pA[1], dstp(0,1,0));
  gload16(pB[0], dstp(1,0,0)); gload16(pB[1], dstp(1,1,0));
  gload16(pA[0] + 64, dstp(0,0,1));
  gload16(pB[0] + 64, dstp(1,0,1));
  asm volatile("s_waitcnt vmcnt(2)" ::: "memory");   // tile0 landed
  __builtin_amdgcn_s_barrier();
  asm volatile("" ::: "memory");

  bf8 af[4], bv0[2], bv1[2];
  for (int t = 0; t < NT; ++t) {
    const int d = t & 1;
    const int t1o = ((t + 1 < NT) ? t + 1 : t - 1) * 64;   // clamp: benign re-stage
    const int t2o = ((t + 2 < NT) ? t + 2 : t) * 64;
    const char* Ld = Lc + d * 32768;
    const char* A0s = Ld;
    const char* A1s = Ld + 8192;
    const char* B0s = Ld + 16384;
    const char* B1s = Ld + 24576;

    // P0 (MH0,NH0): read af<-A0, bv0<-B0; stage B-h1(t+1) -> buf d^1
    #pragma unroll
    for (int m = 0; m < 2; ++m)
      #pragma unroll
      for (int k = 0; k < 2; ++k) af[m*2+k] = rd(A0s, wm*32 + m*16 + lnlo, k);
    #pragma unroll
    for (int k = 0; k < 2; ++k) bv0[k] = rd(B0s, wn*16 + lnlo, k);
    gload16(pB[1] + t1o, dstp(1,1,d^1));
    asm volatile("" ::: "memory");
    __builtin_amdgcn_s_barrier();
    __builtin_amdgcn_s_setprio(1);
    #pragma unroll
    for (int m = 0; m < 2; ++m) {
      acc[m][0] = __builtin_amdgcn_mfma_f32_16x16x32_bf16(af[m*2+0], bv0[0], acc[m][0], 0,0,0);
      acc[m][0] = __builtin_amdgcn_mfma_f32_16x16x32_bf16(af[m*2+1], bv0[1], acc[m][0], 0,0,0);
    }
    __builtin_amdgcn_s_setprio(0);
    __builtin_amdgcn_s_barrier();
    asm volatile("" ::: "memory");

    // P1 (MH0,NH1): read bv1<-B1 (af reused); stage A-h1(t+1) -> buf d^1
    #pragma unroll
    for (int k = 0; k < 2; ++k) bv1[k] = rd(B1s, wn*16 + lnlo, k);
    gload16(pA[1] + t1o, dstp(0,1,d^1));
    asm volatile("" ::: "memory");
    __builtin_amdgcn_s_barrier();
    __builtin_amdgcn_s_setprio(1);
    #pragma unroll
    for (int m = 0; m < 2; ++m) {
      acc[m][1] = __builtin_amdgcn_mfma_f32_16x16x32_bf16(af[m*2+0], bv1[0], acc[m][1], 0,0,0);
      acc[m][1] = __builtin_amdgcn_mfma_f32_16x16x32_bf16(af[m*2+1], bv1[1], acc[m][1], 0,0,0);
    }
    __builtin_amdgcn_s_setprio(0);
    __builtin_amdgcn_s_barrier();
    asm volatile("" ::: "memory");

    // P2 (MH1,NH0): read af<-A1 (bv0 reused); stage A-h0(t+2) -> buf d (A0 last read P0)
    #pragma unroll
    for (int m = 0; m < 2; ++m)
      #pragma unroll
      for (int k = 0; k < 2; ++k) af[m*2+k] = rd(A1s, wm*32 + m*16 + lnlo, k);
    gload16(pA[0] + t2o, dstp(0,0,d));
    asm volatile("" ::: "memory");
    __builtin_amdgcn_s_barrier();
    __builtin_amdgcn_s_setprio(1);
    #pragma unroll
    for (int m = 0; m < 2; ++m) {
      acc[2+m][0] = __builtin_amdgcn_mfma_f32_16x16x32_bf16(af[m*2+0], bv0[0], acc[2+m][0], 0,0,0);
      acc[2+m][0] = __builtin_amdgcn_mfma_f32_16x16x32_bf16(af[m*2+1], bv0[1], acc[2+m][0], 0,0,0);
    }
    __builtin_amdgcn_s_setprio(0);
    __builtin_amdgcn_s_barrier();
    asm volatile("" ::: "memory");

    // P3 (MH1,NH1): no reads; stage B-h0(t+2) -> buf d (B0 last read P0); GEND vmcnt(2)
    gload16(pB[0] + t2o, dstp(1,0,d));
    asm volatile("" ::: "memory");
    __builtin_amdgcn_s_barrier();
    __builtin_amdgcn_s_setprio(1);
    #pragma unroll
    for (int m = 0; m < 2; ++m) {
      acc[2+m][1] = __builtin_amdgcn_mfma_f32_16x16x32_bf16(af[m*2+0], bv1[0], acc[2+m][1], 0,0,0);
      acc[2+m][1] = __builtin_amdgcn_mfma_f32_16x16x32_bf16(af[m*2+1], bv1[1], acc[2+m][1], 0,0,0);
    }
    __builtin_amdgcn_s_setprio(0);
    asm volatile("s_waitcnt vmcnt(2)" ::: "memory");   // tile t+1 fully landed
    __builtin_amdgcn_s_barrier();
    asm volatile("" ::: "memory");
  }

  // epilogue: C/D map col=lane&15, row=(lane>>4)*4+r
  #pragma unroll
  for (int mi = 0; mi < 4; ++mi) {
    const long row = M0 + (mi >> 1) * 64 + wm * 32 + (mi & 1) * 16 + lnhi * 4;
    #pragma unroll
    for (int ni = 0; ni < 2; ++ni) {
      const long col = N0 + ni * 64 + wn * 16 + lnlo;
      if constexpr (MODE == 0) {
        float* Of = (float*)Og + (long)blockIdx.z * 4096 * 768;
        #pragma unroll
        for (int r = 0; r < 4; ++r) Of[(row + r) * 768 + col] = acc[mi][ni][r];
      } else if constexpr (MODE == 1) {
        __hip_bfloat16* Ob = (__hip_bfloat16*)Og + (long)blockIdx.z * 4096 * 4096;
        #pragma unroll
        for (int r = 0; r < 4; ++r)
          *(unsigned short*)&Ob[(row + r) * 4096 + col] = f2bf(acc[mi][ni][r] * scale);
      } else {
        const float bvl = bias[col];
        if (col < 1536) {
          __hip_bfloat16* O = (__hip_bfloat16*)Og;
          #pragma unroll
          for (int r = 0; r < 4; ++r)
            *(unsigned short*)&O[(row + r) * 1536 + col] = f2bf(acc[mi][ni][r] + bvl);
        } else {
          __hip_bfloat16* O2 = (__hip_bfloat16*)Og2;
          bf4 v;
          #pragma unroll
          for (int r = 0; r < 4; ++r) v[r] = (short)f2bf(acc[mi][ni][r] + bvl);
          *(bf4*)&O2[(col - 1536) * 8192 + row] = v;
        }
      }
    }
  }
}

// ---------------- row softmax in place, row = 4096 bf16 ----------------
__global__ __launch_bounds__(256)
void k_softmax(__hip_bfloat16* __restrict__ P) {
  const int S = 4096;
  __hip_bfloat16* p = P + (long)blockIdx.x * S;
  const int tid = threadIdx.x, lane = tid & 63, wave = tid >> 6;
  __shared__ float red[8];
  float x[16];
  bf8 a = *(const bf8*)&p[tid * 16];
  bf8 b = *(const bf8*)&p[tid * 16 + 8];
  #pragma unroll
  for (int j = 0; j < 8; ++j) { x[j] = bf2f((unsigned short)a[j]); x[8 + j] = bf2f((unsigned short)b[j]); }
  float mx = x[0];
  #pragma unroll
  for (int j = 1; j < 16; ++j) mx = fmaxf(mx, x[j]);
  #pragma unroll
  for (int o = 32; o; o >>= 1) mx = fmaxf(mx, __shfl_xor(mx, o));
  if (lane == 0) red[wave] = mx;
  __syncthreads();
  mx = fmaxf(fmaxf(red[0], red[1]), fmaxf(red[2], red[3]));
  float s = 0.0f;
  #pragma unroll
  for (int j = 0; j < 16; ++j) { x[j] = __expf(x[j] - mx); s += x[j]; }
  #pragma unroll
  for (int o = 32; o; o >>= 1) s += __shfl_xor(s, o);
  if (lane == 0) red[4 + wave] = s;
  __syncthreads();
  const float inv = 1.0f / (red[4] + red[5] + red[6] + red[7]);
  union { bf8 v; unsigned short h[8]; } u0, u1;
  #pragma unroll
  for (int j = 0; j < 8; ++j) { u0.h[j] = f2bf(x[j] * inv); u1.h[j] = f2bf(x[8 + j] * inv); }
  *(bf8*)&p[tid * 16] = u0.v;
  *(bf8*)&p[tid * 16 + 8] = u1.v;
}

extern "C" void kernel_launch(void* const* d_in, const int* in_sizes, int n_in,
                              void* d_out, int out_size, void* d_ws, size_t ws_size,
                              hipStream_t stream) {
  const float* x  = (const float*)d_in[0];
  const float* Wq = (const float*)d_in[1]; const float* bq = (const float*)d_in[2];
  const float* Wk = (const float*)d_in[3]; const float* bk = (const float*)d_in[4];
  const float* Wv = (const float*)d_in[5]; const float* bv = (const float*)d_in[6];
  const float* Aq = (const float*)d_in[7]; const float* Bq = (const float*)d_in[8];
  const float* Ak = (const float*)d_in[9]; const float* Bk = (const float*)d_in[10];
  const float* Av = (const float*)d_in[11]; const float* Bv = (const float*)d_in[12];

  // ws layout (bf16 elems), ~121 MB
  __hip_bfloat16* Xb   = (__hip_bfloat16*)d_ws;        // [8192][768]
  __hip_bfloat16* WeA  = Xb  + 6291456;                // [2304][768]
  __hip_bfloat16* QKb  = WeA + 1769472;                // [8192][1536] (Q 0-767, K 768-1535)
  __hip_bfloat16* Vt   = QKb + 12582912;               // [768][8192]
  __hip_bfloat16* Pb   = Vt  + 6291456;                // [2][4096][4096]
  float*          bcat = (float*)(Pb + 33554432);      // [2304]
  float* out = (float*)d_out;

  k_cast<<<3072, 256, 0, stream>>>(x, Xb);
  k_fold3<<<6912, 256, 0, stream>>>(Wq, Aq, Bq, Wk, Ak, Bk, Wv, Av, Bv,
                                    bq, bk, bv, WeA, bcat);

  // projections: M=8192, N=2304, K=768
  k_g128<3><<<dim3(64, 18, 1), 512, 0, stream>>>(Xb, WeA, bcat, QKb, Vt, 1.0f);
  // scores: per batch M=N=4096, K=768, *1/sqrt(768)
  const float sc = 0.036084391824351615f;
  k_g128<1><<<dim3(32, 32, 2), 512, 0, stream>>>(QKb, nullptr, nullptr, Pb, nullptr, sc);
  k_softmax<<<8192, 256, 0, stream>>>(Pb);
  // PV: per batch M=4096, N=768, K=4096
  k_g128<0><<<dim3(32, 6, 2), 512, 0, stream>>>(Pb, Vt, nullptr, out, nullptr, 1.0f);
}

// Round 5
// 219.862 us; speedup vs baseline: 1.2129x; 1.0074x over previous
//
#include <hip/hip_runtime.h>
#include <hip/hip_bf16.h>
#include <math.h>

// LoRA attention, MI355X bf16-MFMA pipeline, round 5.
// 128x128x64 GEMM, 8 waves (2m x 4n), TWO fat phases per K-tile (8 MFMA each,
// 4 barriers/K-tile), 64 KiB LDS -> 2 blocks/CU, counted vmcnt(3), T1/T2/T5.

typedef __attribute__((ext_vector_type(4))) float f32x4;
typedef __attribute__((ext_vector_type(8))) short bf8;   // 8 x bf16
typedef __attribute__((ext_vector_type(4))) short bf4;   // 4 x bf16

__device__ __forceinline__ float bf2f(unsigned short b) {
  union { unsigned u; float f; } c; c.u = ((unsigned)b) << 16; return c.f;
}
__device__ __forceinline__ unsigned short f2bf(float f) {
  union { float f; unsigned u; } c; c.f = f;
  return (unsigned short)((c.u + 0x7fffu + ((c.u >> 16) & 1u)) >> 16);
}
__device__ __forceinline__ void gload16(const void* g, void* l) {
  __builtin_amdgcn_global_load_lds((const __attribute__((address_space(1))) void*)g,
                                   (__attribute__((address_space(3))) void*)l, 16, 0, 0);
}

// ---------------- cast fp32 -> bf16 ----------------
__global__ __launch_bounds__(256)
void k_cast(const float* __restrict__ x, __hip_bfloat16* __restrict__ o) {
  long i = ((long)blockIdx.x * 256 + threadIdx.x) * 8;
  float4 a = *(const float4*)&x[i];
  float4 b = *(const float4*)&x[i + 4];
  union { bf8 v; unsigned short h[8]; } u;
  u.h[0] = f2bf(a.x); u.h[1] = f2bf(a.y); u.h[2] = f2bf(a.z); u.h[3] = f2bf(a.w);
  u.h[4] = f2bf(b.x); u.h[5] = f2bf(b.y); u.h[6] = f2bf(b.z); u.h[7] = f2bf(b.w);
  *(bf8*)&o[i] = u.v;
}

// ---------------- Weff = W + B@A, concat [2304][768] bf16, + bias concat ----------------
__global__ __launch_bounds__(256)
void k_fold3(const float* __restrict__ W0, const float* __restrict__ A0, const float* __restrict__ B0,
             const float* __restrict__ W1, const float* __restrict__ A1, const float* __restrict__ B1,
             const float* __restrict__ W2, const float* __restrict__ A2, const float* __restrict__ B2,
             const float* __restrict__ bq, const float* __restrict__ bk, const float* __restrict__ bv,
             __hip_bfloat16* __restrict__ out, float* __restrict__ bcat) {
  int idx = blockIdx.x * 256 + threadIdx.x;
  if (idx < 2304)
    bcat[idx] = (idx < 768) ? bq[idx] : (idx < 1536) ? bk[idx - 768] : bv[idx - 1536];
  int t = idx / 589824, j = idx - t * 589824;
  const float* W = (t == 0) ? W0 : (t == 1) ? W1 : W2;
  const float* A = (t == 0) ? A0 : (t == 1) ? A1 : A2;
  const float* Bl = (t == 0) ? B0 : (t == 1) ? B1 : B2;
  int d = j % 768, o = j / 768;
  float acc = W[j];
  #pragma unroll
  for (int r = 0; r < 32; ++r) acc += Bl[o * 32 + r] * A[r * 768 + d];
  out[idx] = __float2bfloat16(acc);
}

// ---------------- 128x128x64 8-wave 2-fat-phase GEMM ----------------
// Out[m][n] = scale * sum_k A[m][k] * B[n][k]
// MODE 0: PV   (A=P ld4096, B=Vt ld8192 +z*4096, fp32 out [4096][768])
// MODE 1: scores (A=Q ld1536, B=A+768, bf16 out ld4096, *scale)
// MODE 3: proj (col<1536 -> bf16 [8192][1536] +bias; else Vt [768][8192] +bias)
// Waves: wm=w>>2 (64-row half), wn=w&3 (32-col quarter). acc[4][2].
template<int MODE>
__global__ __launch_bounds__(512, 4)
void k_g128(const __hip_bfloat16* __restrict__ Ag, const __hip_bfloat16* __restrict__ Bg,
            const float* __restrict__ bias, void* __restrict__ Og, void* __restrict__ Og2,
            float scale)
{
  __shared__ short lds[32768];   // 64 KiB: [buf2][opA/B][half2][64x64 bf16]
  constexpr int NT = (MODE == 0) ? 64 : 12;
  const int tid = threadIdx.x, w = tid >> 6, lane = tid & 63;
  const int wm = w >> 2, wn = w & 3;
  const int lnlo = lane & 15, lnhi = lane >> 4;

  // T1 XCD swizzle; N-fast tile mapping
  const int gy = gridDim.y;
  const int nwg = gridDim.x * gy;
  const int w0 = blockIdx.y * gridDim.x + blockIdx.x;
  const int wid = (w0 & 7) * (nwg >> 3) + (w0 >> 3);
  const long M0 = (long)(wid / gy) * 128;
  const long N0 = (long)(wid % gy) * 128;

  const __hip_bfloat16 *A, *B; long lda, ldb;
  if constexpr (MODE == 0) {
    A = Ag + (long)blockIdx.z * 4096 * 4096; lda = 4096;
    B = Bg + (long)blockIdx.z * 4096;        ldb = 8192;
  } else if constexpr (MODE == 1) {
    A = Ag + (long)blockIdx.z * 4096 * 1536; B = A + 768; lda = 1536; ldb = 1536;
  } else {
    A = Ag; B = Bg; lda = 768; ldb = 768;
  }

  // staging: half-tile (64 rows x 64 k) = 1 gload16/thread; source col pre-swizzled (T2)
  const int srow = w * 8 + (lane >> 3);
  const int scol = (((lane & 7) ^ (lane >> 3)) << 3);
  const __hip_bfloat16* pA[2] = { A + (M0 + srow) * lda + scol, A + (M0 + 64 + srow) * lda + scol };
  const __hip_bfloat16* pB[2] = { B + (N0 + srow) * ldb + scol, B + (N0 + 64 + srow) * ldb + scol };
  char* Lc = (char*)lds;
  auto dstp = [&](int op, int h, int d) { return Lc + d * 32768 + op * 16384 + h * 8192 + w * 1024; };
  auto rd = [&](const char* base, int row, int k) -> bf8 {   // T2-swizzled LDS read
    const int sb = ((k << 6) + (lnhi << 4)) ^ ((row & 7) << 4);
    return *(const bf8*)(base + row * 128 + sb);
  };

  f32x4 acc[4][2] = {};   // [m-frag 0..3][n-frag 0..1]

  // prologue: tile0 complete (4 halves), tile1 {B-h0,B-h1,A-h0}
  gload16(pB[0],      dstp(1,0,0)); gload16(pB[1],      dstp(1,1,0));
  gload16(pA[0],      dstp(0,0,0)); gload16(pA[1],      dstp(0,1,0));
  gload16(pB[0] + 64, dstp(1,0,1)); gload16(pB[1] + 64, dstp(1,1,1));
  gload16(pA[0] + 64, dstp(0,0,1));
  asm volatile("s_waitcnt vmcnt(3)" ::: "memory");   // tile0's 4 landed
  __builtin_amdgcn_s_barrier();
  asm volatile("" ::: "memory");

  bf8 af[2][2], bv[2][2];
  for (int t = 0; t < NT; ++t) {
    const int d = t & 1, dx = d ^ 1;
    const int t1o = ((t + 1 < NT) ? t + 1 : t - 1) * 64;   // dest buf never read if clamped
    const int t2o = ((t + 2 < NT) ? t + 2 : t) * 64;       // restage same data: benign
    const char* Ab = Lc + d * 32768;
    const char* Bb = Ab + 16384;

    // ---- P0: m-half 0; read af(h0) + ALL bv; stage A-h1(t+1) -> buf dx ----
    #pragma unroll
    for (int m = 0; m < 2; ++m)
      #pragma unroll
      for (int k = 0; k < 2; ++k) af[m][k] = rd(Ab, wm * 64 + m * 16 + lnlo, k);
    #pragma unroll
    for (int n = 0; n < 2; ++n)
      #pragma unroll
      for (int k = 0; k < 2; ++k) bv[n][k] = rd(Bb, wn * 32 + n * 16 + lnlo, k);
    gload16(pA[1] + t1o, dstp(0,1,dx));
    asm volatile("" ::: "memory");
    __builtin_amdgcn_s_barrier();
    __builtin_amdgcn_s_setprio(1);
    #pragma unroll
    for (int m = 0; m < 2; ++m)
      #pragma unroll
      for (int n = 0; n < 2; ++n) {
        acc[m][n] = __builtin_amdgcn_mfma_f32_16x16x32_bf16(af[m][0], bv[n][0], acc[m][n], 0,0,0);
        acc[m][n] = __builtin_amdgcn_mfma_f32_16x16x32_bf16(af[m][1], bv[n][1], acc[m][n], 0,0,0);
      }
    __builtin_amdgcn_s_setprio(0);
    __builtin_amdgcn_s_barrier();
    asm volatile("" ::: "memory");

    // ---- P1: m-half 1; read af(h1), reuse bv; stage B(t+2)+A-h0(t+2) -> buf d ----
    #pragma unroll
    for (int m = 0; m < 2; ++m)
      #pragma unroll
      for (int k = 0; k < 2; ++k) af[m][k] = rd(Ab, wm * 64 + 32 + m * 16 + lnlo, k);
    gload16(pB[0] + t2o, dstp(1,0,d));
    gload16(pB[1] + t2o, dstp(1,1,d));
    gload16(pA[0] + t2o, dstp(0,0,d));
    asm volatile("" ::: "memory");
    __builtin_amdgcn_s_barrier();
    __builtin_amdgcn_s_setprio(1);
    #pragma unroll
    for (int m = 0; m < 2; ++m)
      #pragma unroll
      for (int n = 0; n < 2; ++n) {
        acc[2+m][n] = __builtin_amdgcn_mfma_f32_16x16x32_bf16(af[m][0], bv[n][0], acc[2+m][n], 0,0,0);
        acc[2+m][n] = __builtin_amdgcn_mfma_f32_16x16x32_bf16(af[m][1], bv[n][1], acc[2+m][n], 0,0,0);
      }
    __builtin_amdgcn_s_setprio(0);
    asm volatile("s_waitcnt vmcnt(3)" ::: "memory");   // tile t+1 fully landed
    __builtin_amdgcn_s_barrier();
    asm volatile("" ::: "memory");
  }

  // epilogue: C/D map col=lane&15, row=(lane>>4)*4+r
  #pragma unroll
  for (int mi = 0; mi < 4; ++mi) {
    const long row = M0 + wm * 64 + mi * 16 + lnhi * 4;
    #pragma unroll
    for (int ni = 0; ni < 2; ++ni) {
      const long col = N0 + wn * 32 + ni * 16 + lnlo;
      if constexpr (MODE == 0) {
        float* Of = (float*)Og + (long)blockIdx.z * 4096 * 768;
        #pragma unroll
        for (int r = 0; r < 4; ++r) Of[(row + r) * 768 + col] = acc[mi][ni][r];
      } else if constexpr (MODE == 1) {
        __hip_bfloat16* Ob = (__hip_bfloat16*)Og + (long)blockIdx.z * 4096 * 4096;
        #pragma unroll
        for (int r = 0; r < 4; ++r)
          *(unsigned short*)&Ob[(row + r) * 4096 + col] = f2bf(acc[mi][ni][r] * scale);
      } else {
        const float bvl = bias[col];
        if (col < 1536) {
          __hip_bfloat16* O = (__hip_bfloat16*)Og;
          #pragma unroll
          for (int r = 0; r < 4; ++r)
            *(unsigned short*)&O[(row + r) * 1536 + col] = f2bf(acc[mi][ni][r] + bvl);
        } else {
          __hip_bfloat16* O2 = (__hip_bfloat16*)Og2;
          bf4 v;
          #pragma unroll
          for (int r = 0; r < 4; ++r) v[r] = (short)f2bf(acc[mi][ni][r] + bvl);
          *(bf4*)&O2[(col - 1536) * 8192 + row] = v;
        }
      }
    }
  }
}

// ---------------- row softmax in place, row = 4096 bf16 ----------------
__global__ __launch_bounds__(256)
void k_softmax(__hip_bfloat16* __restrict__ P) {
  const int S = 4096;
  __hip_bfloat16* p = P + (long)blockIdx.x * S;
  const int tid = threadIdx.x, lane = tid & 63, wave = tid >> 6;
  __shared__ float red[8];
  float x[16];
  bf8 a = *(const bf8*)&p[tid * 16];
  bf8 b = *(const bf8*)&p[tid * 16 + 8];
  #pragma unroll
  for (int j = 0; j < 8; ++j) { x[j] = bf2f((unsigned short)a[j]); x[8 + j] = bf2f((unsigned short)b[j]); }
  float mx = x[0];
  #pragma unroll
  for (int j = 1; j < 16; ++j) mx = fmaxf(mx, x[j]);
  #pragma unroll
  for (int o = 32; o; o >>= 1) mx = fmaxf(mx, __shfl_xor(mx, o));
  if (lane == 0) red[wave] = mx;
  __syncthreads();
  mx = fmaxf(fmaxf(red[0], red[1]), fmaxf(red[2], red[3]));
  float s = 0.0f;
  #pragma unroll
  for (int j = 0; j < 16; ++j) { x[j] = __expf(x[j] - mx); s += x[j]; }
  #pragma unroll
  for (int o = 32; o; o >>= 1) s += __shfl_xor(s, o);
  if (lane == 0) red[4 + wave] = s;
  __syncthreads();
  const float inv = 1.0f / (red[4] + red[5] + red[6] + red[7]);
  union { bf8 v; unsigned short h[8]; } u0, u1;
  #pragma unroll
  for (int j = 0; j < 8; ++j) { u0.h[j] = f2bf(x[j] * inv); u1.h[j] = f2bf(x[8 + j] * inv); }
  *(bf8*)&p[tid * 16] = u0.v;
  *(bf8*)&p[tid * 16 + 8] = u1.v;
}

extern "C" void kernel_launch(void* const* d_in, const int* in_sizes, int n_in,
                              void* d_out, int out_size, void* d_ws, size_t ws_size,
                              hipStream_t stream) {
  const float* x  = (const float*)d_in[0];
  const float* Wq = (const float*)d_in[1]; const float* bq = (const float*)d_in[2];
  const float* Wk = (const float*)d_in[3]; const float* bk = (const float*)d_in[4];
  const float* Wv = (const float*)d_in[5]; const float* bv = (const float*)d_in[6];
  const float* Aq = (const float*)d_in[7]; const float* Bq = (const float*)d_in[8];
  const float* Ak = (const float*)d_in[9]; const float* Bk = (const float*)d_in[10];
  const float* Av = (const float*)d_in[11]; const float* Bv = (const float*)d_in[12];

  // ws layout (bf16 elems), ~121 MB
  __hip_bfloat16* Xb   = (__hip_bfloat16*)d_ws;        // [8192][768]
  __hip_bfloat16* WeA  = Xb  + 6291456;                // [2304][768]
  __hip_bfloat16* QKb  = WeA + 1769472;                // [8192][1536] (Q 0-767, K 768-1535)
  __hip_bfloat16* Vt   = QKb + 12582912;               // [768][8192]
  __hip_bfloat16* Pb   = Vt  + 6291456;                // [2][4096][4096]
  float*          bcat = (float*)(Pb + 33554432);      // [2304]
  float* out = (float*)d_out;

  k_cast<<<3072, 256, 0, stream>>>(x, Xb);
  k_fold3<<<6912, 256, 0, stream>>>(Wq, Aq, Bq, Wk, Ak, Bk, Wv, Av, Bv,
                                    bq, bk, bv, WeA, bcat);

  // projections: M=8192, N=2304, K=768
  k_g128<3><<<dim3(64, 18, 1), 512, 0, stream>>>(Xb, WeA, bcat, QKb, Vt, 1.0f);
  // scores: per batch M=N=4096, K=768, *1/sqrt(768)
  const float sc = 0.036084391824351615f;
  k_g128<1><<<dim3(32, 32, 2), 512, 0, stream>>>(QKb, nullptr, nullptr, Pb, nullptr, sc);
  k_softmax<<<8192, 256, 0, stream>>>(Pb);
  // PV: per batch M=4096, N=768, K=4096 (384 blocks, all resident at 2/CU)
  k_g128<0><<<dim3(32, 6, 2), 512, 0, stream>>>(Pb, Vt, nullptr, out, nullptr, 1.0f);
}

// Round 6
// 207.696 us; speedup vs baseline: 1.2840x; 1.0586x over previous
//
#include <hip/hip_runtime.h>
#include <hip/hip_bf16.h>
#include <math.h>

// LoRA attention, MI355X bf16-MFMA pipeline, round 6.
// scores = 256x256x64 8-phase (m201 geometry: per-wave 128x64, 64 MFMA / 24 ds_read),
// epilogue writes P'=exp(s*scale) + atomic row-sums (softmax kernel eliminated),
// PV/proj = 128x128x64 2-fat-phase, PV epilogue divides by row-sum.

typedef __attribute__((ext_vector_type(4))) float f32x4;
typedef __attribute__((ext_vector_type(8))) short bf8;   // 8 x bf16
typedef __attribute__((ext_vector_type(4))) short bf4;   // 4 x bf16

__device__ __forceinline__ float bf2f(unsigned short b) {
  union { unsigned u; float f; } c; c.u = ((unsigned)b) << 16; return c.f;
}
__device__ __forceinline__ unsigned short f2bf(float f) {
  union { float f; unsigned u; } c; c.f = f;
  return (unsigned short)((c.u + 0x7fffu + ((c.u >> 16) & 1u)) >> 16);
}
__device__ __forceinline__ void gload16(const void* g, void* l) {
  __builtin_amdgcn_global_load_lds((const __attribute__((address_space(1))) void*)g,
                                   (__attribute__((address_space(3))) void*)l, 16, 0, 0);
}

// ---------------- cast fp32 -> bf16 ----------------
__global__ __launch_bounds__(256)
void k_cast(const float* __restrict__ x, __hip_bfloat16* __restrict__ o) {
  long i = ((long)blockIdx.x * 256 + threadIdx.x) * 8;
  float4 a = *(const float4*)&x[i];
  float4 b = *(const float4*)&x[i + 4];
  union { bf8 v; unsigned short h[8]; } u;
  u.h[0] = f2bf(a.x); u.h[1] = f2bf(a.y); u.h[2] = f2bf(a.z); u.h[3] = f2bf(a.w);
  u.h[4] = f2bf(b.x); u.h[5] = f2bf(b.y); u.h[6] = f2bf(b.z); u.h[7] = f2bf(b.w);
  *(bf8*)&o[i] = u.v;
}

// ---------------- Weff = W + B@A, concat [2304][768] bf16, + bias concat ----------------
__global__ __launch_bounds__(256)
void k_fold3(const float* __restrict__ W0, const float* __restrict__ A0, const float* __restrict__ B0,
             const float* __restrict__ W1, const float* __restrict__ A1, const float* __restrict__ B1,
             const float* __restrict__ W2, const float* __restrict__ A2, const float* __restrict__ B2,
             const float* __restrict__ bq, const float* __restrict__ bk, const float* __restrict__ bv,
             __hip_bfloat16* __restrict__ out, float* __restrict__ bcat) {
  int idx = blockIdx.x * 256 + threadIdx.x;
  if (idx < 2304)
    bcat[idx] = (idx < 768) ? bq[idx] : (idx < 1536) ? bk[idx - 768] : bv[idx - 1536];
  int t = idx / 589824, j = idx - t * 589824;
  const float* W = (t == 0) ? W0 : (t == 1) ? W1 : W2;
  const float* A = (t == 0) ? A0 : (t == 1) ? A1 : A2;
  const float* Bl = (t == 0) ? B0 : (t == 1) ? B1 : B2;
  int d = j % 768, o = j / 768;
  float acc = W[j];
  #pragma unroll
  for (int r = 0; r < 32; ++r) acc += Bl[o * 32 + r] * A[r * 768 + d];
  out[idx] = __float2bfloat16(acc);
}

// ================= scores: 256x256x64, 8 waves (2Mx4N), per-wave 128x64 =================
// P'[m][n] = exp(scale * sum_k Q[m][k]*K[n][k]), row-sums atomically into lsum.
// Quadrants per K-tile: Q0(mh0,nh0: read af_lo 8 + bv_lo 4), Q1(mh0,nh1: bv_hi 4),
// Q2(mh1,nh0: af_hi 8), Q3(mh1,nh1: 0). 16 MFMA each. Stage 1 half-tile/phase.
__global__ __launch_bounds__(512, 2)
void k_sc256(const __hip_bfloat16* __restrict__ QK, __hip_bfloat16* __restrict__ P,
             float* __restrict__ lsum, float scale)
{
  __shared__ short lds[65536];   // 128 KiB: [buf2][opA/B][half2][128x64 bf16]
  const int tid = threadIdx.x, w = tid >> 6, lane = tid & 63;
  const int wm = w >> 2, wn = w & 3;
  const int lnlo = lane & 15, lnhi = lane >> 4;
  const long z = blockIdx.z;

  // T1 XCD swizzle, N-fast
  const int gy = gridDim.y;                      // 16
  const int nwg = gridDim.x * gy;                // 256
  const int w0 = blockIdx.y * gridDim.x + blockIdx.x;
  const int wid = (w0 & 7) * (nwg >> 3) + (w0 >> 3);
  const long M0 = (long)(wid / gy) * 256;
  const long N0 = (long)(wid % gy) * 256;

  const __hip_bfloat16* A = QK + z * (4096L * 1536);   // Q
  const __hip_bfloat16* B = A + 768;                   // K
  const long ld = 1536;

  // staging: half-tile = 128 rows x 64 cols; thread covers rows (srow, srow+64), T2-preswizzled col
  const int srow = tid >> 3;
  const int scol = (((tid & 7) ^ (srow & 7)) << 3);
  const __hip_bfloat16* pA[2] = { A + (M0 + srow) * ld + scol, A + (M0 + 128 + srow) * ld + scol };
  const __hip_bfloat16* pB[2] = { B + (N0 + srow) * ld + scol, B + (N0 + 128 + srow) * ld + scol };

  char* Lc = (char*)lds;
  auto slot = [&](int op, int h, int d) { return Lc + ((d << 16) | (op << 15) | (h << 14)); };
  auto stage = [&](const __hip_bfloat16* src, char* dst) {
    gload16(src, dst + w * 1024);
    gload16(src + 64 * ld, dst + 8192 + w * 1024);
  };
  auto rd = [&](const char* base, int row, int k) -> bf8 {   // T2-swizzled read
    const int sb = ((k << 6) + (lnhi << 4)) ^ ((row & 7) << 4);
    return *(const bf8*)(base + row * 128 + sb);
  };

  f32x4 acc[8][4] = {};
  bf8 af[4][2], bv[4][2];
  const int bro = (wn & 1) * 64;   // row offset within the wave's B-half

#define PHASE(MH, NH, SRC, DST, GEND) do {                                          \
    if (NH == 0) {                                                                  \
      _Pragma("unroll")                                                             \
      for (int j = 0; j < 4; ++j)                                                   \
        _Pragma("unroll")                                                           \
        for (int k = 0; k < 2; ++k) af[j][k] = rd(Abase, MH * 64 + j * 16 + lnlo, k); \
    }                                                                               \
    if (MH == 0) {                                                                  \
      _Pragma("unroll")                                                             \
      for (int nn = 0; nn < 2; ++nn)                                                \
        _Pragma("unroll")                                                           \
        for (int k = 0; k < 2; ++k)                                                 \
          bv[NH * 2 + nn][k] = rd(Bbase, bro + NH * 32 + nn * 16 + lnlo, k);        \
    }                                                                               \
    stage(SRC, DST);                                                                \
    asm volatile("" ::: "memory");                                                  \
    __builtin_amdgcn_s_barrier();                                                   \
    __builtin_amdgcn_s_setprio(1);                                                  \
    _Pragma("unroll")                                                               \
    for (int j = 0; j < 4; ++j)                                                     \
      _Pragma("unroll")                                                             \
      for (int nn = 0; nn < 2; ++nn) {                                              \
        acc[MH*4+j][NH*2+nn] = __builtin_amdgcn_mfma_f32_16x16x32_bf16(             \
            af[j][0], bv[NH*2+nn][0], acc[MH*4+j][NH*2+nn], 0, 0, 0);               \
        acc[MH*4+j][NH*2+nn] = __builtin_amdgcn_mfma_f32_16x16x32_bf16(             \
            af[j][1], bv[NH*2+nn][1], acc[MH*4+j][NH*2+nn], 0, 0, 0);               \
      }                                                                             \
    __builtin_amdgcn_s_setprio(0);                                                  \
    if (GEND) asm volatile("s_waitcnt vmcnt(4)" ::: "memory");                      \
    __builtin_amdgcn_s_barrier();                                                   \
    asm volatile("" ::: "memory");                                                  \
  } while (0)

  // prologue: tile0 {B0,B1,A0,A1}->buf0, tile1 {B0,B1}->buf1
  stage(pB[0], slot(1,0,0)); stage(pB[1], slot(1,1,0));
  stage(pA[0], slot(0,0,0)); stage(pA[1], slot(0,1,0));
  stage(pB[0] + 64, slot(1,0,1)); stage(pB[1] + 64, slot(1,1,1));
  asm volatile("s_waitcnt vmcnt(4)" ::: "memory");   // tile0's 8 loads landed
  __builtin_amdgcn_s_barrier();
  asm volatile("" ::: "memory");

  const int NTT = 12;   // K=768 -> 12 K-tiles, 6 iterations
  for (int i = 0; i < 6; ++i) {
    const int t = 2 * i;
    const int o1 = (t + 1) * 64;
    const int o2 = ((t + 2 < NTT) ? t + 2 : t) * 64;       // clamp: identical restage
    const int o3 = ((t + 3 < NTT) ? t + 3 : t + 1) * 64;
    {  // tile t in buf0
      const char* Abase = slot(0, wm, 0);
      const char* Bbase = slot(1, wn >> 1, 0);
      PHASE(0, 0, pA[0] + o1, slot(0,0,1), false);   // stage A0(t+1)->buf1
      PHASE(0, 1, pA[1] + o1, slot(0,1,1), false);   // A1(t+1)->buf1
      PHASE(1, 0, pB[0] + o2, slot(1,0,0), false);   // B0(t+2)->buf0 (B buf0 free after P2)
      PHASE(1, 1, pB[1] + o2, slot(1,1,0), true);    // B1(t+2)->buf0; vmcnt(4): t+1 landed
    }
    {  // tile t+1 in buf1
      const char* Abase = slot(0, wm, 1);
      const char* Bbase = slot(1, wn >> 1, 1);
      PHASE(0, 0, pA[0] + o2, slot(0,0,0), false);   // A0(t+2)->buf0 (A buf0 free after P3)
      PHASE(0, 1, pA[1] + o2, slot(0,1,0), false);   // A1(t+2)->buf0
      PHASE(1, 0, pB[0] + o3, slot(1,0,1), false);   // B0(t+3)->buf1 (B buf1 free after P6)
      PHASE(1, 1, pB[1] + o3, slot(1,1,1), true);    // B1(t+3)->buf1; vmcnt(4): t+2 landed
    }
  }
#undef PHASE

  // epilogue: C/D map col=lane&15, row=(lane>>4)*4+r; write P'=exp, atomic row-sums
  __hip_bfloat16* Pz = P + z * (4096L * 4096);
  float* lz = lsum + z * 4096;
  #pragma unroll
  for (int mf = 0; mf < 8; ++mf) {
    const long row = M0 + wm * 128 + mf * 16 + lnhi * 4;
    float rs[4] = {0.f, 0.f, 0.f, 0.f};
    #pragma unroll
    for (int nf = 0; nf < 4; ++nf) {
      const long col = N0 + wn * 64 + nf * 16 + lnlo;
      #pragma unroll
      for (int r = 0; r < 4; ++r) {
        const float e = __expf(fminf(acc[mf][nf][r] * scale, 70.0f));
        rs[r] += e;
        *(unsigned short*)&Pz[(row + r) * 4096 + col] = f2bf(e);
      }
    }
    #pragma unroll
    for (int r = 0; r < 4; ++r) {
      float v = rs[r];
      v += __shfl_xor(v, 1); v += __shfl_xor(v, 2);
      v += __shfl_xor(v, 4); v += __shfl_xor(v, 8);
      if (lnlo == 0) atomicAdd(&lz[row + r], v);
    }
  }
}

// ---------------- 128x128x64 8-wave 2-fat-phase GEMM (proj + PV) ----------------
// MODE 0: PV (A=P' ld4096, B=Vt ld8192 +z*4096, fp32 out /lsum)
// MODE 3: proj (col<1536 -> bf16 [8192][1536] +bias; else Vt [768][8192] +bias)
template<int MODE>
__global__ __launch_bounds__(512, 4)
void k_g128(const __hip_bfloat16* __restrict__ Ag, const __hip_bfloat16* __restrict__ Bg,
            const float* __restrict__ bias, void* __restrict__ Og, void* __restrict__ Og2,
            const float* __restrict__ lsum, float scale)
{
  __shared__ short lds[32768];   // 64 KiB
  constexpr int NT = (MODE == 0) ? 64 : 12;
  const int tid = threadIdx.x, w = tid >> 6, lane = tid & 63;
  const int wm = w >> 2, wn = w & 3;
  const int lnlo = lane & 15, lnhi = lane >> 4;

  const int gy = gridDim.y;
  const int nwg = gridDim.x * gy;
  const int w0 = blockIdx.y * gridDim.x + blockIdx.x;
  const int wid = (w0 & 7) * (nwg >> 3) + (w0 >> 3);
  const long M0 = (long)(wid / gy) * 128;
  const long N0 = (long)(wid % gy) * 128;

  const __hip_bfloat16 *A, *B; long lda, ldb;
  if constexpr (MODE == 0) {
    A = Ag + (long)blockIdx.z * 4096 * 4096; lda = 4096;
    B = Bg + (long)blockIdx.z * 4096;        ldb = 8192;
  } else {
    A = Ag; B = Bg; lda = 768; ldb = 768;
  }

  const int srow = w * 8 + (lane >> 3);
  const int scol = (((lane & 7) ^ (lane >> 3)) << 3);
  const __hip_bfloat16* pA[2] = { A + (M0 + srow) * lda + scol, A + (M0 + 64 + srow) * lda + scol };
  const __hip_bfloat16* pB[2] = { B + (N0 + srow) * ldb + scol, B + (N0 + 64 + srow) * ldb + scol };
  char* Lc = (char*)lds;
  auto dstp = [&](int op, int h, int d) { return Lc + d * 32768 + op * 16384 + h * 8192 + w * 1024; };
  auto rd = [&](const char* base, int row, int k) -> bf8 {
    const int sb = ((k << 6) + (lnhi << 4)) ^ ((row & 7) << 4);
    return *(const bf8*)(base + row * 128 + sb);
  };

  f32x4 acc[4][2] = {};

  gload16(pB[0],      dstp(1,0,0)); gload16(pB[1],      dstp(1,1,0));
  gload16(pA[0],      dstp(0,0,0)); gload16(pA[1],      dstp(0,1,0));
  gload16(pB[0] + 64, dstp(1,0,1)); gload16(pB[1] + 64, dstp(1,1,1));
  gload16(pA[0] + 64, dstp(0,0,1));
  asm volatile("s_waitcnt vmcnt(3)" ::: "memory");
  __builtin_amdgcn_s_barrier();
  asm volatile("" ::: "memory");

  bf8 af[2][2], bv[2][2];
  for (int t = 0; t < NT; ++t) {
    const int d = t & 1, dx = d ^ 1;
    const int t1o = ((t + 1 < NT) ? t + 1 : t - 1) * 64;
    const int t2o = ((t + 2 < NT) ? t + 2 : t) * 64;
    const char* Ab = Lc + d * 32768;
    const char* Bb = Ab + 16384;

    #pragma unroll
    for (int m = 0; m < 2; ++m)
      #pragma unroll
      for (int k = 0; k < 2; ++k) af[m][k] = rd(Ab, wm * 64 + m * 16 + lnlo, k);
    #pragma unroll
    for (int n = 0; n < 2; ++n)
      #pragma unroll
      for (int k = 0; k < 2; ++k) bv[n][k] = rd(Bb, wn * 32 + n * 16 + lnlo, k);
    gload16(pA[1] + t1o, dstp(0,1,dx));
    asm volatile("" ::: "memory");
    __builtin_amdgcn_s_barrier();
    __builtin_amdgcn_s_setprio(1);
    #pragma unroll
    for (int m = 0; m < 2; ++m)
      #pragma unroll
      for (int n = 0; n < 2; ++n) {
        acc[m][n] = __builtin_amdgcn_mfma_f32_16x16x32_bf16(af[m][0], bv[n][0], acc[m][n], 0,0,0);
        acc[m][n] = __builtin_amdgcn_mfma_f32_16x16x32_bf16(af[m][1], bv[n][1], acc[m][n], 0,0,0);
      }
    __builtin_amdgcn_s_setprio(0);
    __builtin_amdgcn_s_barrier();
    asm volatile("" ::: "memory");

    #pragma unroll
    for (int m = 0; m < 2; ++m)
      #pragma unroll
      for (int k = 0; k < 2; ++k) af[m][k] = rd(Ab, wm * 64 + 32 + m * 16 + lnlo, k);
    gload16(pB[0] + t2o, dstp(1,0,d));
    gload16(pB[1] + t2o, dstp(1,1,d));
    gload16(pA[0] + t2o, dstp(0,0,d));
    asm volatile("" ::: "memory");
    __builtin_amdgcn_s_barrier();
    __builtin_amdgcn_s_setprio(1);
    #pragma unroll
    for (int m = 0; m < 2; ++m)
      #pragma unroll
      for (int n = 0; n < 2; ++n) {
        acc[2+m][n] = __builtin_amdgcn_mfma_f32_16x16x32_bf16(af[m][0], bv[n][0], acc[2+m][n], 0,0,0);
        acc[2+m][n] = __builtin_amdgcn_mfma_f32_16x16x32_bf16(af[m][1], bv[n][1], acc[2+m][n], 0,0,0);
      }
    __builtin_amdgcn_s_setprio(0);
    asm volatile("s_waitcnt vmcnt(3)" ::: "memory");
    __builtin_amdgcn_s_barrier();
    asm volatile("" ::: "memory");
  }

  #pragma unroll
  for (int mi = 0; mi < 4; ++mi) {
    const long row = M0 + wm * 64 + mi * 16 + lnhi * 4;
    if constexpr (MODE == 0) {
      float* Of = (float*)Og + (long)blockIdx.z * 4096 * 768;
      const float* lz = lsum + (long)blockIdx.z * 4096;
      float linv[4];
      #pragma unroll
      for (int r = 0; r < 4; ++r) linv[r] = 1.0f / lz[row + r];
      #pragma unroll
      for (int ni = 0; ni < 2; ++ni) {
        const long col = N0 + wn * 32 + ni * 16 + lnlo;
        #pragma unroll
        for (int r = 0; r < 4; ++r) Of[(row + r) * 768 + col] = acc[mi][ni][r] * linv[r];
      }
    } else {
      #pragma unroll
      for (int ni = 0; ni < 2; ++ni) {
        const long col = N0 + wn * 32 + ni * 16 + lnlo;
        const float bvl = bias[col];
        if (col < 1536) {
          __hip_bfloat16* O = (__hip_bfloat16*)Og;
          #pragma unroll
          for (int r = 0; r < 4; ++r)
            *(unsigned short*)&O[(row + r) * 1536 + col] = f2bf(acc[mi][ni][r] + bvl);
        } else {
          __hip_bfloat16* O2 = (__hip_bfloat16*)Og2;
          bf4 v;
          #pragma unroll
          for (int r = 0; r < 4; ++r) v[r] = (short)f2bf(acc[mi][ni][r] + bvl);
          *(bf4*)&O2[(col - 1536) * 8192 + row] = v;
        }
      }
    }
  }
}

extern "C" void kernel_launch(void* const* d_in, const int* in_sizes, int n_in,
                              void* d_out, int out_size, void* d_ws, size_t ws_size,
                              hipStream_t stream) {
  const float* x  = (const float*)d_in[0];
  const float* Wq = (const float*)d_in[1]; const float* bq = (const float*)d_in[2];
  const float* Wk = (const float*)d_in[3]; const float* bk = (const float*)d_in[4];
  const float* Wv = (const float*)d_in[5]; const float* bv = (const float*)d_in[6];
  const float* Aq = (const float*)d_in[7]; const float* Bq = (const float*)d_in[8];
  const float* Ak = (const float*)d_in[9]; const float* Bk = (const float*)d_in[10];
  const float* Av = (const float*)d_in[11]; const float* Bv = (const float*)d_in[12];

  // ws layout (bf16 elems), ~121 MB
  __hip_bfloat16* Xb   = (__hip_bfloat16*)d_ws;        // [8192][768]
  __hip_bfloat16* WeA  = Xb  + 6291456;                // [2304][768]
  __hip_bfloat16* QKb  = WeA + 1769472;                // [8192][1536] (Q 0-767, K 768-1535)
  __hip_bfloat16* Vt   = QKb + 12582912;               // [768][8192]
  __hip_bfloat16* Pb   = Vt  + 6291456;                // [2][4096][4096] unnormalized exp
  float*          bcat = (float*)(Pb + 33554432);      // [2304]
  float*          lsum = bcat + 2304;                  // [2][4096] row sums
  float* out = (float*)d_out;

  k_cast<<<3072, 256, 0, stream>>>(x, Xb);
  k_fold3<<<6912, 256, 0, stream>>>(Wq, Aq, Bq, Wk, Ak, Bk, Wv, Av, Bv,
                                    bq, bk, bv, WeA, bcat);
  hipMemsetAsync(lsum, 0, 8192 * sizeof(float), stream);

  // projections: M=8192, N=2304, K=768
  k_g128<3><<<dim3(64, 18, 1), 512, 0, stream>>>(Xb, WeA, bcat, QKb, Vt, nullptr, 1.0f);
  // scores + exp + rowsum: per batch M=N=4096, K=768
  const float sc = 0.036084391824351615f;
  k_sc256<<<dim3(16, 16, 2), 512, 0, stream>>>(QKb, Pb, lsum, sc);
  // PV: per batch M=4096, N=768, K=4096; epilogue normalizes by lsum
  k_g128<0><<<dim3(32, 6, 2), 512, 0, stream>>>(Pb, Vt, nullptr, out, nullptr, lsum, 1.0f);
}